// Round 1
// baseline (42197.574 us; speedup 1.0000x reference)
//
#include <hip/hip_runtime.h>
#include <math.h>

#define T_STEPS 2048
#define B_SZ 32
#define F_SZ 512
#define H_SZ 512
#define H4_SZ 2048
#define NC_SZ 64

typedef _Float16 f16x8 __attribute__((ext_vector_type(8)));
typedef float f32x4 __attribute__((ext_vector_type(4)));

// Persistent 2-layer LSTM.
// Grid: 256 blocks x 256 threads. Cluster c = bid>>6 owns batch rows [8c,8c+8).
// Block j = bid&63 owns hidden units [8j,8j+8) of both layers (c-state in regs).
// Iteration it: layer0 step t=it (uses h0[it-1], x[it]) and layer1 step t=it-1
// (uses h0[it-1], h1[it-2]) -> one cluster barrier per iteration.
__global__ __launch_bounds__(256, 1) void lstm_persistent(
    const float* __restrict__ feats,
    const float* __restrict__ Wi0, const float* __restrict__ Wh0,
    const float* __restrict__ bh0,
    const float* __restrict__ Wi1, const float* __restrict__ Wh1,
    const float* __restrict__ bh1,
    const float* __restrict__ Wout, const float* __restrict__ bout,
    float* __restrict__ out,
    _Float16* __restrict__ h0buf,   // [2][32][512] fp16 ring
    _Float16* __restrict__ h1buf,   // [2][32][512] fp16 ring
    float* __restrict__ h1fin,      // [32][512] f32 final h1
    unsigned* __restrict__ bar)     // per cluster: [c*64]=cnt, [c*64+32]=gen
{
    const int tid  = threadIdx.x;
    const int lane = tid & 63;
    const int wv   = tid >> 6;          // wave 0..3 = K-quarter
    const int bid  = blockIdx.x;
    const int cl   = bid >> 6;          // cluster 0..3
    const int jb   = bid & 63;          // block in cluster
    const int hbase = jb * 8;
    const int bbase = cl * 8;

    __shared__ float zs[2048];          // [L][wave][ct][row8][col16] f32 partials

    // ---- one-time: weight fragments into registers (fp16) ----
    // layer0 stacked K rows: [Wi0(512); Wh0(512)]  (A0 = [x | h0])
    // layer1 stacked K rows: [Wh1(512); Wi1(512)]  (A1 = [h1 | h0])
    // B frag (16x16x32): lane holds col = lane&15, k = (lane>>4)*8 + i
    f16x8 w0[2][8], w1[2][8];
    {
        const int colf = lane & 15;
        const int kloW = (lane >> 4) * 8;
        #pragma unroll
        for (int ct = 0; ct < 2; ++ct) {
            const int cc   = ct * 16 + colf;                       // local z-col 0..31
            const int jcol = (cc >> 3) * H_SZ + hbase + (cc & 7);  // gate*512 + unit
            #pragma unroll
            for (int s = 0; s < 8; ++s) {
                const int k0 = 256 * wv + 32 * s + kloW;
                f16x8 f0, f1;
                #pragma unroll
                for (int i = 0; i < 8; ++i) {
                    const int k = k0 + i;
                    const float v0 = (k < 512) ? Wi0[k * H4_SZ + jcol]
                                               : Wh0[(k - 512) * H4_SZ + jcol];
                    const float v1 = (k < 512) ? Wh1[k * H4_SZ + jcol]
                                               : Wi1[(k - 512) * H4_SZ + jcol];
                    f0[i] = (_Float16)v0;
                    f1[i] = (_Float16)v1;
                }
                w0[ct][s] = f0;
                w1[ct][s] = f1;
            }
        }
    }

    // gate-thread state (wave 0, tid<64): (b,u) = (tid>>3, tid&7)
    float c0 = 0.f, c1 = 0.f;
    float bias0[4], bias1[4];
    const int gb = tid >> 3, gu = tid & 7;
    if (tid < 64) {
        #pragma unroll
        for (int g = 0; g < 4; ++g) {
            bias0[g] = bh0[g * H_SZ + hbase + gu];
            bias1[g] = bh1[g * H_SZ + hbase + gu];
        }
    }

    const int arow = lane & 7;            // batch row (lanes 8-15 duplicate 0-7)
    const int klo  = (lane >> 4) * 8;
    unsigned* cntp = bar + cl * 64;
    unsigned* genp = bar + cl * 64 + 32;

    for (int it = 0; it <= T_STEPS; ++it) {
        // ---- A fragment loads (direct from global) ----
        // A frag: lane holds row = lane&15 (batch, dup), k = (lane>>4)*8 + i
        f16x8 a0[8], a1[8];
        if (wv < 2) {
            if (it < T_STEPS) {   // x part of layer0 (K quarter [256*wv, +256))
                const float* xrow = feats
                    + ((size_t)(bbase + arow) * T_STEPS + (size_t)it) * F_SZ
                    + 256 * wv + klo;
                #pragma unroll
                for (int s = 0; s < 8; ++s) {
                    const float4 p0 = *(const float4*)(xrow + 32 * s);
                    const float4 p1 = *(const float4*)(xrow + 32 * s + 4);
                    f16x8 t;
                    t[0]=(_Float16)p0.x; t[1]=(_Float16)p0.y;
                    t[2]=(_Float16)p0.z; t[3]=(_Float16)p0.w;
                    t[4]=(_Float16)p1.x; t[5]=(_Float16)p1.y;
                    t[6]=(_Float16)p1.z; t[7]=(_Float16)p1.w;
                    a0[s] = t;
                }
            }
            if (it > 0) {         // h1[it-2] part of layer1
                const _Float16* hp = h1buf + (size_t)(it & 1) * (B_SZ * H_SZ)
                                     + (bbase + arow) * H_SZ + 256 * wv + klo;
                #pragma unroll
                for (int s = 0; s < 8; ++s) a1[s] = *(const f16x8*)(hp + 32 * s);
            }
        } else {                  // h0[it-1]: shared by layer0 (k>=512) and layer1 (k>=512)
            const _Float16* hp = h0buf + (size_t)((it + 1) & 1) * (B_SZ * H_SZ)
                                 + (bbase + arow) * H_SZ + 256 * (wv - 2) + klo;
            #pragma unroll
            for (int s = 0; s < 8; ++s) a0[s] = *(const f16x8*)(hp + 32 * s);
        }

        // ---- MFMA: layer0 (t=it) ----
        if (it < T_STEPS) {
            f32x4 p0 = {0.f,0.f,0.f,0.f}, p1 = {0.f,0.f,0.f,0.f};
            #pragma unroll
            for (int s = 0; s < 8; ++s) {
                p0 = __builtin_amdgcn_mfma_f32_16x16x32_f16(a0[s], w0[0][s], p0, 0, 0, 0);
                p1 = __builtin_amdgcn_mfma_f32_16x16x32_f16(a0[s], w0[1][s], p1, 0, 0, 0);
            }
            if (lane < 32) {       // D: row=(lane>>4)*4+q, col=lane&15 ; rows 0..7 real
                const int row = (lane >> 4) * 4, col = lane & 15;
                #pragma unroll
                for (int q = 0; q < 4; ++q) {
                    zs[((0*4 + wv)*2 + 0)*128 + (row + q)*16 + col] = p0[q];
                    zs[((0*4 + wv)*2 + 1)*128 + (row + q)*16 + col] = p1[q];
                }
            }
        }
        // ---- MFMA: layer1 (t=it-1) ----
        if (it > 0) {
            f32x4 p0 = {0.f,0.f,0.f,0.f}, p1 = {0.f,0.f,0.f,0.f};
            if (wv < 2) {
                #pragma unroll
                for (int s = 0; s < 8; ++s) {
                    p0 = __builtin_amdgcn_mfma_f32_16x16x32_f16(a1[s], w1[0][s], p0, 0, 0, 0);
                    p1 = __builtin_amdgcn_mfma_f32_16x16x32_f16(a1[s], w1[1][s], p1, 0, 0, 0);
                }
            } else {
                #pragma unroll
                for (int s = 0; s < 8; ++s) {
                    p0 = __builtin_amdgcn_mfma_f32_16x16x32_f16(a0[s], w1[0][s], p0, 0, 0, 0);
                    p1 = __builtin_amdgcn_mfma_f32_16x16x32_f16(a0[s], w1[1][s], p1, 0, 0, 0);
                }
            }
            if (lane < 32) {
                const int row = (lane >> 4) * 4, col = lane & 15;
                #pragma unroll
                for (int q = 0; q < 4; ++q) {
                    zs[((1*4 + wv)*2 + 0)*128 + (row + q)*16 + col] = p0[q];
                    zs[((1*4 + wv)*2 + 1)*128 + (row + q)*16 + col] = p1[q];
                }
            }
        }
        __syncthreads();

        // ---- gates (wave 0 only): reduce 4 K-partials, update c, emit h ----
        if (tid < 64) {
            if (it < T_STEPS) {
                float z[4];
                #pragma unroll
                for (int g = 0; g < 4; ++g) {
                    const int cc = g * 8 + gu;
                    const int ct = cc >> 4, col = cc & 15;
                    float v = bias0[g];
                    #pragma unroll
                    for (int ww = 0; ww < 4; ++ww)
                        v += zs[((0*4 + ww)*2 + ct)*128 + gb*16 + col];
                    z[g] = v;
                }
                const float ig = 1.f / (1.f + expf(-z[0]));
                const float fg = 1.f / (1.f + expf(-z[1]));
                const float gg = tanhf(z[2]);
                const float og = 1.f / (1.f + expf(-z[3]));
                c0 = fg * c0 + ig * gg;
                const float hh = og * tanhf(c0);
                h0buf[(size_t)(it & 1)*(B_SZ*H_SZ) + (bbase + gb)*H_SZ + hbase + gu] = (_Float16)hh;
            }
            if (it > 0) {
                float z[4];
                #pragma unroll
                for (int g = 0; g < 4; ++g) {
                    const int cc = g * 8 + gu;
                    const int ct = cc >> 4, col = cc & 15;
                    float v = bias1[g];
                    #pragma unroll
                    for (int ww = 0; ww < 4; ++ww)
                        v += zs[((1*4 + ww)*2 + ct)*128 + gb*16 + col];
                    z[g] = v;
                }
                const float ig = 1.f / (1.f + expf(-z[0]));
                const float fg = 1.f / (1.f + expf(-z[1]));
                const float gg = tanhf(z[2]);
                const float og = 1.f / (1.f + expf(-z[3]));
                c1 = fg * c1 + ig * gg;
                const float hh = og * tanhf(c1);
                h1buf[(size_t)((it + 1) & 1)*(B_SZ*H_SZ) + (bbase + gb)*H_SZ + hbase + gu] = (_Float16)hh;
                if (it == T_STEPS)
                    h1fin[(bbase + gb)*H_SZ + hbase + gu] = hh;
            }
            __threadfence();   // all h stores come from wave 0; order before arrive
        }
        __syncthreads();

        // ---- cluster barrier (sense counter + generation flag) ----
        if (tid == 0) {
            const unsigned old = __hip_atomic_fetch_add(
                cntp, 1u, __ATOMIC_ACQ_REL, __HIP_MEMORY_SCOPE_AGENT);
            if (old == 63u) {
                __hip_atomic_store(cntp, 0u, __ATOMIC_RELAXED, __HIP_MEMORY_SCOPE_AGENT);
                __hip_atomic_store(genp, (unsigned)(it + 1), __ATOMIC_RELEASE,
                                   __HIP_MEMORY_SCOPE_AGENT);
            }
        }
        if (lane == 0) {   // each wave's lane 0 spins, then acquires
            while (__hip_atomic_load(genp, __ATOMIC_RELAXED, __HIP_MEMORY_SCOPE_AGENT)
                   < (unsigned)(it + 1)) { }
            (void)__hip_atomic_load(genp, __ATOMIC_ACQUIRE, __HIP_MEMORY_SCOPE_AGENT);
        }
        __syncthreads();
    }

    // ---- output head: block (cl,jb) -> out[bbase+b][jb], f32 ----
    if (tid < 8) {
        const int b = bbase + tid;
        const float* hr = h1fin + b * H_SZ;
        float acc = bout[jb];
        for (int k = 0; k < H_SZ; ++k)
            acc += hr[k] * Wout[k * NC_SZ + jb];
        out[b * NC_SZ + jb] = acc;
    }
}

extern "C" void kernel_launch(void* const* d_in, const int* in_sizes, int n_in,
                              void* d_out, int out_size, void* d_ws, size_t ws_size,
                              hipStream_t stream) {
    const float* feats = (const float*)d_in[0];
    const float* Wi0   = (const float*)d_in[1];
    const float* Wh0   = (const float*)d_in[2];
    const float* bh0   = (const float*)d_in[3];
    const float* Wi1   = (const float*)d_in[4];
    const float* Wh1   = (const float*)d_in[5];
    const float* bh1   = (const float*)d_in[6];
    const float* Wout  = (const float*)d_in[7];
    const float* bout  = (const float*)d_in[8];

    char* ws = (char*)d_ws;
    _Float16* h0buf = (_Float16*)(ws);            // 64 KB
    _Float16* h1buf = (_Float16*)(ws + 65536);    // 64 KB
    float*    h1fin = (float*)(ws + 131072);      // 64 KB
    unsigned* bar   = (unsigned*)(ws + 196608);   // 1 KB

    // zero ring buffers (h[-1]=0), final buffer, and barrier state each call
    hipMemsetAsync(d_ws, 0, 197632, stream);

    lstm_persistent<<<dim3(256), dim3(256), 0, stream>>>(
        feats, Wi0, Wh0, bh0, Wi1, Wh1, bh1, Wout, bout,
        (float*)d_out, h0buf, h1buf, h1fin, bar);
}

// Round 2
// 31716.681 us; speedup vs baseline: 1.3305x; 1.3305x over previous
//
#include <hip/hip_runtime.h>
#include <math.h>

#define T_STEPS 2048
#define B_SZ 32
#define F_SZ 512
#define H_SZ 512
#define H4_SZ 2048
#define NC_SZ 64
#define NBLK 64
#define RING (B_SZ * H_SZ)   // 16384 fp16 elements per ring slot

typedef _Float16 f16x8 __attribute__((ext_vector_type(8)));
typedef float f32x4 __attribute__((ext_vector_type(4)));

#define TIDX(l, w, rt, ct) (((((l)*4 + (w))*2 + (rt))*2 + (ct)))

// Coherence-point (LLC) 16B load as two 8B relaxed agent atomics: emits
// global_load_dwordx2 sc0 sc1 -> bypasses (possibly stale) per-XCD L2.
__device__ __forceinline__ f16x8 load_h8_cp(const _Float16* p) {
    union { f16x8 v; unsigned long long q[2]; } u;
    u.q[0] = __hip_atomic_load((const unsigned long long*)p,
                               __ATOMIC_RELAXED, __HIP_MEMORY_SCOPE_AGENT);
    u.q[1] = __hip_atomic_load((const unsigned long long*)(p + 4),
                               __ATOMIC_RELAXED, __HIP_MEMORY_SCOPE_AGENT);
    return u.v;
}

// Single-cluster persistent 2-layer LSTM.
// 64 blocks x 256 thr. Block j owns hidden units [8j,8j+8) of BOTH layers
// (c-state in regs). Full batch B=32 per block via 2 MFMA row-tiles.
// Iter it: layer0 t=it, layer1 t=it-1 -> one distributed flag-barrier/iter.
// All cross-block traffic = relaxed agent atomics (sc0sc1, no cache maint).
__global__ __launch_bounds__(256, 1) void lstm_persistent(
    const float* __restrict__ feats,
    const float* __restrict__ Wi0, const float* __restrict__ Wh0,
    const float* __restrict__ bh0,
    const float* __restrict__ Wi1, const float* __restrict__ Wh1,
    const float* __restrict__ bh1,
    const float* __restrict__ Wout, const float* __restrict__ bout,
    float* __restrict__ out,
    _Float16* __restrict__ h0buf,   // [2][32][512] fp16 ring
    _Float16* __restrict__ h1buf,   // [2][32][512] fp16 ring
    float* __restrict__ h1fin,      // [32][512] f32 final h1
    unsigned* __restrict__ flags)   // [64] per-block completion flags
{
    const int tid   = threadIdx.x;
    const int lane  = tid & 63;
    const int wv    = tid >> 6;          // wave 0..3 = K-quarter of stacked K=1024
    const int jb    = blockIdx.x;        // 0..63
    const int hbase = jb * 8;
    const int rlane = lane & 15;
    const int klo   = (lane >> 4) * 8;

    __shared__ float zs[32 * 272];       // 32 tiles of 16x17 f32 partials
    __shared__ float ps[256];

    // ---- one-time: weight fragments (fp16) ----
    // layer0 stacked K: [Wi0(512); Wh0(512)], A0 = [x | h0]
    // layer1 stacked K: [Wh1(512); Wi1(512)], A1 = [h1 | h0]
    // B frag 16x16x32: lane holds col=lane&15, k=(lane>>4)*8+i  (verified r1)
    f16x8 wf0[2][8], wf1[2][8];
    #pragma unroll
    for (int ct = 0; ct < 2; ++ct) {
        const int cc   = ct * 16 + rlane;
        const int jcol = (cc >> 3) * H_SZ + hbase + (cc & 7);
        #pragma unroll
        for (int ks = 0; ks < 8; ++ks) {
            const int k0 = 256 * wv + 32 * ks + klo;
            f16x8 f0, f1;
            #pragma unroll
            for (int i = 0; i < 8; ++i) {
                const int k = k0 + i;
                const float v0 = (k < H_SZ) ? Wi0[(size_t)k * H4_SZ + jcol]
                                            : Wh0[(size_t)(k - H_SZ) * H4_SZ + jcol];
                const float v1 = (k < H_SZ) ? Wh1[(size_t)k * H4_SZ + jcol]
                                            : Wi1[(size_t)(k - H_SZ) * H4_SZ + jcol];
                f0[i] = (_Float16)v0;
                f1[i] = (_Float16)v1;
            }
            wf0[ct][ks] = f0;
            wf1[ct][ks] = f1;
        }
    }

    // gate-thread mapping: all 256 threads, one (batch,unit) each
    const int gb = tid >> 3, gu = tid & 7;
    const int grow = gb & 15, grt = gb >> 4;
    float c0 = 0.f, c1 = 0.f;
    float bias0[4], bias1[4];
    #pragma unroll
    for (int g = 0; g < 4; ++g) {
        bias0[g] = bh0[g * H_SZ + hbase + gu];
        bias1[g] = bh1[g * H_SZ + hbase + gu];
    }

    f16x8 xf[2][8];   // prefetched+converted x fragments (waves 0,1)

#define PREFETCH_X(tt_) do {                                                         \
    if (wv < 2 && (tt_) < T_STEPS) {                                                 \
        _Pragma("unroll")                                                            \
        for (int rt = 0; rt < 2; ++rt) {                                             \
            const float* xr = feats                                                  \
                + ((size_t)(rt * 16 + rlane) * T_STEPS + (size_t)(tt_)) * F_SZ       \
                + 256 * wv + klo;                                                    \
            _Pragma("unroll")                                                        \
            for (int ks = 0; ks < 8; ++ks) {                                         \
                const float4 p0 = *(const float4*)(xr + 32 * ks);                    \
                const float4 p1 = *(const float4*)(xr + 32 * ks + 4);                \
                f16x8 t;                                                             \
                t[0] = (_Float16)p0.x; t[1] = (_Float16)p0.y;                        \
                t[2] = (_Float16)p0.z; t[3] = (_Float16)p0.w;                        \
                t[4] = (_Float16)p1.x; t[5] = (_Float16)p1.y;                        \
                t[6] = (_Float16)p1.z; t[7] = (_Float16)p1.w;                        \
                xf[rt][ks] = t;                                                      \
            }                                                                        \
        }                                                                            \
    }                                                                                \
} while (0)

    PREFETCH_X(0);

    for (int it = 0; it <= T_STEPS; ++it) {
        // ---- distributed barrier: wait until all blocks completed iter it-1 ----
        if (tid < 64) {
            unsigned f;
            do {
                f = __hip_atomic_load(&flags[lane], __ATOMIC_RELAXED,
                                      __HIP_MEMORY_SCOPE_AGENT);
            } while (!__all((int)(f >= (unsigned)it)));
        }
        __syncthreads();

        // ---- h fragments from LLC ----
        // wv>=2: h0[it-1] (slot (it+1)&1), shared by layer0 & layer1
        // wv<2 : h1[it-2] (slot it&1) for layer1
        f16x8 hA[2][8];
        if (wv >= 2) {
            const _Float16* hp = h0buf + (size_t)((it + 1) & 1) * RING;
            #pragma unroll
            for (int rt = 0; rt < 2; ++rt)
                #pragma unroll
                for (int ks = 0; ks < 8; ++ks)
                    hA[rt][ks] = load_h8_cp(hp + (rt * 16 + rlane) * H_SZ
                                            + 256 * (wv - 2) + 32 * ks + klo);
        } else if (it > 0) {
            const _Float16* hp = h1buf + (size_t)(it & 1) * RING;
            #pragma unroll
            for (int rt = 0; rt < 2; ++rt)
                #pragma unroll
                for (int ks = 0; ks < 8; ++ks)
                    hA[rt][ks] = load_h8_cp(hp + (rt * 16 + rlane) * H_SZ
                                            + 256 * wv + 32 * ks + klo);
        }

        const int r0 = (lane >> 4) * 4, ccl = lane & 15;

        // ---- layer0 MFMA (t=it): A = x (wv<2, ready in regs) or h0 (wv>=2) ----
        if (it < T_STEPS) {
            f32x4 a00 = {0,0,0,0}, a01 = {0,0,0,0}, a10 = {0,0,0,0}, a11 = {0,0,0,0};
            #pragma unroll
            for (int ks = 0; ks < 8; ++ks) {
                const f16x8 ar0 = (wv < 2) ? xf[0][ks] : hA[0][ks];
                const f16x8 ar1 = (wv < 2) ? xf[1][ks] : hA[1][ks];
                a00 = __builtin_amdgcn_mfma_f32_16x16x32_f16(ar0, wf0[0][ks], a00, 0, 0, 0);
                a01 = __builtin_amdgcn_mfma_f32_16x16x32_f16(ar0, wf0[1][ks], a01, 0, 0, 0);
                a10 = __builtin_amdgcn_mfma_f32_16x16x32_f16(ar1, wf0[0][ks], a10, 0, 0, 0);
                a11 = __builtin_amdgcn_mfma_f32_16x16x32_f16(ar1, wf0[1][ks], a11, 0, 0, 0);
            }
            #pragma unroll
            for (int q = 0; q < 4; ++q) {
                zs[TIDX(0, wv, 0, 0) * 272 + (r0 + q) * 17 + ccl] = a00[q];
                zs[TIDX(0, wv, 0, 1) * 272 + (r0 + q) * 17 + ccl] = a01[q];
                zs[TIDX(0, wv, 1, 0) * 272 + (r0 + q) * 17 + ccl] = a10[q];
                zs[TIDX(0, wv, 1, 1) * 272 + (r0 + q) * 17 + ccl] = a11[q];
            }
        }
        // ---- layer1 MFMA (t=it-1): A = h1 (wv<2) or h0 (wv>=2) = hA ----
        if (it > 0) {
            f32x4 a00 = {0,0,0,0}, a01 = {0,0,0,0}, a10 = {0,0,0,0}, a11 = {0,0,0,0};
            #pragma unroll
            for (int ks = 0; ks < 8; ++ks) {
                a00 = __builtin_amdgcn_mfma_f32_16x16x32_f16(hA[0][ks], wf1[0][ks], a00, 0, 0, 0);
                a01 = __builtin_amdgcn_mfma_f32_16x16x32_f16(hA[0][ks], wf1[1][ks], a01, 0, 0, 0);
                a10 = __builtin_amdgcn_mfma_f32_16x16x32_f16(hA[1][ks], wf1[0][ks], a10, 0, 0, 0);
                a11 = __builtin_amdgcn_mfma_f32_16x16x32_f16(hA[1][ks], wf1[1][ks], a11, 0, 0, 0);
            }
            #pragma unroll
            for (int q = 0; q < 4; ++q) {
                zs[TIDX(1, wv, 0, 0) * 272 + (r0 + q) * 17 + ccl] = a00[q];
                zs[TIDX(1, wv, 0, 1) * 272 + (r0 + q) * 17 + ccl] = a01[q];
                zs[TIDX(1, wv, 1, 0) * 272 + (r0 + q) * 17 + ccl] = a10[q];
                zs[TIDX(1, wv, 1, 1) * 272 + (r0 + q) * 17 + ccl] = a11[q];
            }
        }
        __syncthreads();

        // ---- gates: reduce 4 K-partials, update c, emit h (relaxed agent stores) ----
        if (it < T_STEPS) {
            float z[4];
            #pragma unroll
            for (int g = 0; g < 4; ++g) {
                const int cc = g * 8 + gu, ct = cc >> 4, col = cc & 15;
                float v = bias0[g];
                #pragma unroll
                for (int w = 0; w < 4; ++w)
                    v += zs[TIDX(0, w, grt, ct) * 272 + grow * 17 + col];
                z[g] = v;
            }
            const float ig = 1.f / (1.f + expf(-z[0]));
            const float fg = 1.f / (1.f + expf(-z[1]));
            const float gg = tanhf(z[2]);
            const float og = 1.f / (1.f + expf(-z[3]));
            c0 = fg * c0 + ig * gg;
            const float hv = og * tanhf(c0);
            const float hpart = __shfl_xor(hv, 1);
            if ((gu & 1) == 0) {   // pack 2 fp16 -> one u32 atomic store
                union { _Float16 h; unsigned short s; } lo, hi;
                lo.h = (_Float16)hv; hi.h = (_Float16)hpart;
                const unsigned pk = (unsigned)lo.s | ((unsigned)hi.s << 16);
                __hip_atomic_store(
                    (unsigned*)(h0buf + (size_t)(it & 1) * RING + gb * H_SZ + hbase + gu),
                    pk, __ATOMIC_RELAXED, __HIP_MEMORY_SCOPE_AGENT);
            }
        }
        if (it > 0) {
            float z[4];
            #pragma unroll
            for (int g = 0; g < 4; ++g) {
                const int cc = g * 8 + gu, ct = cc >> 4, col = cc & 15;
                float v = bias1[g];
                #pragma unroll
                for (int w = 0; w < 4; ++w)
                    v += zs[TIDX(1, w, grt, ct) * 272 + grow * 17 + col];
                z[g] = v;
            }
            const float ig = 1.f / (1.f + expf(-z[0]));
            const float fg = 1.f / (1.f + expf(-z[1]));
            const float gg = tanhf(z[2]);
            const float og = 1.f / (1.f + expf(-z[3]));
            c1 = fg * c1 + ig * gg;
            const float hv = og * tanhf(c1);
            const float hpart = __shfl_xor(hv, 1);
            if ((gu & 1) == 0) {
                union { _Float16 h; unsigned short s; } lo, hi;
                lo.h = (_Float16)hv; hi.h = (_Float16)hpart;
                const unsigned pk = (unsigned)lo.s | ((unsigned)hi.s << 16);
                __hip_atomic_store(
                    (unsigned*)(h1buf + (size_t)((it + 1) & 1) * RING + gb * H_SZ + hbase + gu),
                    pk, __ATOMIC_RELAXED, __HIP_MEMORY_SCOPE_AGENT);
            }
            if (it == T_STEPS) {
                union { float f; unsigned u; } cv; cv.f = hv;
                __hip_atomic_store((unsigned*)(h1fin + gb * H_SZ + hbase + gu),
                                   cv.u, __ATOMIC_RELAXED, __HIP_MEMORY_SCOPE_AGENT);
            }
        }
        // drain all stores to the coherence point, then arrive
        asm volatile("s_waitcnt vmcnt(0)" ::: "memory");
        __syncthreads();
        if (tid == 0)
            __hip_atomic_store(&flags[jb], (unsigned)(it + 1),
                               __ATOMIC_RELAXED, __HIP_MEMORY_SCOPE_AGENT);

        // tail: prefetch + convert x[it+1] during barrier slack
        PREFETCH_X(it + 1);
    }

    // final barrier: all h1fin stores visible
    if (tid < 64) {
        unsigned f;
        do {
            f = __hip_atomic_load(&flags[lane], __ATOMIC_RELAXED,
                                  __HIP_MEMORY_SCOPE_AGENT);
        } while (!__all((int)(f >= (unsigned)(T_STEPS + 1))));
    }
    __syncthreads();

    // ---- output head: block jb -> out[:, jb] ----
    {
        const int b = tid & 31, kc = tid >> 5;
        float part = 0.f;
        for (int k = kc * 64; k < kc * 64 + 64; ++k) {
            union { unsigned u; float f; } cv;
            cv.u = __hip_atomic_load((const unsigned*)(h1fin + b * H_SZ + k),
                                     __ATOMIC_RELAXED, __HIP_MEMORY_SCOPE_AGENT);
            part += cv.f * Wout[(size_t)k * NC_SZ + jb];
        }
        ps[kc * 32 + b] = part;
        __syncthreads();
        if (tid < 32) {
            float acc = bout[jb];
            #pragma unroll
            for (int c = 0; c < 8; ++c) acc += ps[c * 32 + tid];
            out[tid * NC_SZ + jb] = acc;
        }
    }
#undef PREFETCH_X
}

extern "C" void kernel_launch(void* const* d_in, const int* in_sizes, int n_in,
                              void* d_out, int out_size, void* d_ws, size_t ws_size,
                              hipStream_t stream) {
    const float* feats = (const float*)d_in[0];
    const float* Wi0   = (const float*)d_in[1];
    const float* Wh0   = (const float*)d_in[2];
    const float* bh0   = (const float*)d_in[3];
    const float* Wi1   = (const float*)d_in[4];
    const float* Wh1   = (const float*)d_in[5];
    const float* bh1   = (const float*)d_in[6];
    const float* Wout  = (const float*)d_in[7];
    const float* bout  = (const float*)d_in[8];

    char* ws = (char*)d_ws;
    _Float16* h0buf = (_Float16*)(ws);            // 64 KB
    _Float16* h1buf = (_Float16*)(ws + 65536);    // 64 KB
    float*    h1fin = (float*)(ws + 131072);      // 64 KB
    unsigned* flags = (unsigned*)(ws + 196608);   // 256 B

    // zero rings (h[-1]=h[-2]=0), final buf, flags — every call (determinism)
    hipMemsetAsync(d_ws, 0, 196864, stream);

    lstm_persistent<<<dim3(NBLK), dim3(256), 0, stream>>>(
        feats, Wi0, Wh0, bh0, Wi1, Wh1, bh1, Wout, bout,
        (float*)d_out, h0buf, h1buf, h1fin, flags);
}